// Round 1
// 558.911 us; speedup vs baseline: 1.0591x; 1.0591x over previous
//
#include <hip/hip_runtime.h>

#define HDIM 32
#define NBINS 512   // lengths occupy bins 0..256; padded to pow2 for the scan

typedef _Float16 f16x8 __attribute__((ext_vector_type(8)));
typedef _Float16 f16x2 __attribute__((ext_vector_type(2)));
typedef float f32x16 __attribute__((ext_vector_type(16)));
typedef unsigned int u32x4 __attribute__((ext_vector_type(4)));
#define MFMA32(A,B,C) __builtin_amdgcn_mfma_f32_32x32x16_f16((A),(B),(C),0,0,0)

// pack two f32 -> one u32 of 2 f16 (v_cvt_pkrtz_f16_f32, single VALU op)
__device__ __forceinline__ unsigned int pk_f16(float a, float b) {
    return __builtin_bit_cast(unsigned int, __builtin_amdgcn_cvt_pkrtz(a, b));
}
// v_permlane32_swap_b32: a_new = {a.lo, b.lo-from-partner}, b_new = {a.hi-from-partner, b.hi}
__device__ __forceinline__ void pl32swap(unsigned int& a, unsigned int& b) {
    asm("v_permlane32_swap_b32 %0, %1" : "+v"(a), "+v"(b));
}

// empty-asm VGPR pins: make loop-invariant values opaque so the compiler
// CANNOT rematerialize them via per-step global loads (old build: VGPR=44 <
// minimal live set => W_ih/b were re-loaded every timestep)
#define PIN16(a) asm("" : "+v"(a[0]),"+v"(a[1]),"+v"(a[2]),"+v"(a[3]), \
                         "+v"(a[4]),"+v"(a[5]),"+v"(a[6]),"+v"(a[7]), \
                         "+v"(a[8]),"+v"(a[9]),"+v"(a[10]),"+v"(a[11]), \
                         "+v"(a[12]),"+v"(a[13]),"+v"(a[14]),"+v"(a[15]))
#define PIN8(a)  asm("" : "+v"(a[0]),"+v"(a[1]),"+v"(a[2]),"+v"(a[3]), \
                         "+v"(a[4]),"+v"(a[5]),"+v"(a[6]),"+v"(a[7]))

// ---- length-bucketing: counting sort into a permutation (DESCENDING) ----
__global__ __launch_bounds__(256) void hist_kernel(
    const int* __restrict__ l, int* __restrict__ cnt, int nseq)
{
    __shared__ int hc[NBINS];
    for (int k = threadIdx.x; k < NBINS; k += blockDim.x) hc[k] = 0;
    __syncthreads();
    for (int i = blockIdx.x * blockDim.x + threadIdx.x; i < nseq;
         i += gridDim.x * blockDim.x)
        atomicAdd(&hc[l[i]], 1);
    __syncthreads();
    for (int k = threadIdx.x; k < NBINS; k += blockDim.x)
        if (hc[k]) atomicAdd(&cnt[k], hc[k]);
}

// off[t] = sum_{k>t} cnt[k]  (exclusive SUFFIX sum -> longest lengths first)
__global__ __launch_bounds__(NBINS) void scan_kernel(
    const int* __restrict__ cnt, int* __restrict__ off)
{
    __shared__ int sc[NBINS];
    int t = threadIdx.x;
    int v0 = cnt[t];
    sc[t] = v0;
    __syncthreads();
    for (int d = 1; d < NBINS; d <<= 1) {
        int v = (t + d < NBINS) ? sc[t + d] : 0;
        __syncthreads();
        sc[t] += v;
        __syncthreads();
    }
    off[t] = sc[t] - v0;          // strictly-greater suffix sum
}

// Block-aggregated scatter: LDS histogram per block, ONE global atomic per
// touched bin to reserve a range, then LDS cursors for local ranks.
__global__ __launch_bounds__(256) void scatter_kernel(
    const int* __restrict__ l, int* __restrict__ off,
    int* __restrict__ perm, int nseq)
{
    __shared__ int lcur[NBINS];
    const int chunk = (nseq + gridDim.x - 1) / gridDim.x;
    const int lo = blockIdx.x * chunk;
    const int hi = min(nseq, lo + chunk);
    for (int k = threadIdx.x; k < NBINS; k += blockDim.x) lcur[k] = 0;
    __syncthreads();
    for (int i = lo + threadIdx.x; i < hi; i += blockDim.x)
        atomicAdd(&lcur[l[i]], 1);
    __syncthreads();
    for (int k = threadIdx.x; k < NBINS; k += blockDim.x) {
        int c = lcur[k];
        lcur[k] = c ? atomicAdd(&off[k], c) : 0;   // global base for this block
    }
    __syncthreads();
    for (int i = lo + threadIdx.x; i < hi; i += blockDim.x) {
        int p = atomicAdd(&lcur[l[i]], 1);         // LDS cursor = base + rank
        perm[p] = i;
    }
}

// ---- RNN: wave = 32 (length-matched) sequences, MFMA 32x32x16 f16 ----
// Lane: n = lane&31 (seq/column), half = lane>>5.
// A frag f: A[m=n][k=8*half+j] -> W_hh[n*32 + 16f + 8*half + j]   (scaled by S)
// B frag f: B[k][n=lane&31], k = 16f + 8*half + j -> h[k]
// C/D: col=lane&31, row=(r&3)+8*(r>>2)+4*half   [verified mapping]
//
// Per-step changes vs previous version (all VALU-issue reductions):
//  * W_ih/b/W_hh fragments pinned in VGPRs (no per-step rematerializing loads)
//  * 2*log2(e) folded into all weights -> tanh = exp2, add, rcp, fma
//  * D->B relayout = 8 v_cvt_pkrtz + 4 v_permlane32_swap (no ds_bpermute,
//    no cndmask): B-frag pairs (k,k+1) are exactly D-reg pairs (2r,2r+1);
//    swap(P0,P2) yields BOTH words: {ownP0.lo, partnerP2} and {partnerP0, ownP2.hi}
//  * H updated unconditionally (dead columns stay bounded: tanh saturates);
//    output stored at t==len-1 (exec-masked, fires ~once per bucketed wave)
//  * emb in f16 (lossless: values already f16-rounded); depth-2 x prefetch
__global__ __launch_bounds__(64, 4) void rnn_kernel(
    const float* __restrict__ hin, const int* __restrict__ l,
    const int* __restrict__ perm,
    const float* __restrict__ W_ih, const float* __restrict__ W_hh,
    const float* __restrict__ b_ih, const float* __restrict__ b_hh,
    _Float16* __restrict__ emb, int nseq, int tmax)
{
    const int lane = threadIdx.x & 63;
    const int n    = lane & 31;
    const int half = lane >> 5;
    const int pidx = blockIdx.x * 32 + n;
    const bool live = pidx < nseq;
    const int seq  = live ? perm[pidx] : 0;
    const int len  = live ? l[seq] : 0;

    const float S = 2.8853900817779268f;   // 2*log2(e), folded into weights

    // persistent A fragments (W_hh * S in f16), pinned
    unsigned int qw[8];
    {
        f16x8 w[2];
        #pragma unroll
        for (int f = 0; f < 2; ++f)
            #pragma unroll
            for (int j = 0; j < 8; ++j)
                w[f][j] = (_Float16)(W_hh[n * 32 + 16 * f + 8 * half + j] * S);
        u32x4 qa = __builtin_bit_cast(u32x4, w[0]);
        u32x4 qb = __builtin_bit_cast(u32x4, w[1]);
        #pragma unroll
        for (int c = 0; c < 4; ++c) { qw[c] = qa[c]; qw[4 + c] = qb[c]; }
    }
    PIN8(qw);
    const f16x8 WA = __builtin_bit_cast(f16x8, (u32x4){qw[0], qw[1], qw[2], qw[3]});
    const f16x8 WB = __builtin_bit_cast(f16x8, (u32x4){qw[4], qw[5], qw[6], qw[7]});

    // C-init constants for this lane's 16 accumulator rows (fp32-exact input
    // path), scaled by S, pinned
    float bv[16], wv[16];
    #pragma unroll
    for (int r = 0; r < 16; ++r) {
        const int row = (r & 3) + 8 * (r >> 2) + 4 * half;
        bv[r] = (b_ih[row] + b_hh[row]) * S;
        wv[r] = W_ih[row] * S;
    }
    PIN16(bv);
    PIN16(wv);

    // trip count = max length over the wave's 32 sequences (bucketed ~equal)
    int mx = len;
    #pragma unroll
    for (int d = 1; d < 32; d <<= 1) {
        int o = __shfl_xor(mx, d);
        mx = mx > o ? mx : o;
    }
    const int maxlen = mx;

    // output pointer: emb row = 32 f16 = 16 u32; this lane owns u32s
    // [4*half .. +3] (k=8*half..+7) and [8+4*half .. +3] (k=16+8*half..+7)
    unsigned int* po = (unsigned int*)emb + (size_t)seq * 16 + 4 * half;
    if (live && len == 0) {                 // len==0 -> emb stays zero
        const u32x4 z = {0u, 0u, 0u, 0u};
        *(u32x4*)po       = z;
        *(u32x4*)(po + 8) = z;
    }

    const int base = seq * tmax;
    int off = len - 1;                      // x at step t = hin[len-1-t]
    float x0 = hin[base + (off > 0 ? off : 0)];
    float x1 = hin[base + (off - 1 > 0 ? off - 1 : 0)];

    u32x4 H0 = {0u, 0u, 0u, 0u}, H1 = {0u, 0u, 0u, 0u};   // h, f16 B-layout

    for (int t = 0; t < maxlen; ++t) {
        const int off2 = off - 2;
        const float x2 = hin[base + (off2 > 0 ? off2 : 0)];   // depth-2 prefetch

        f32x16 acc;
        #pragma unroll
        for (int r = 0; r < 16; ++r) acc[r] = fmaf(x0, wv[r], bv[r]);
        acc = MFMA32(WA, __builtin_bit_cast(f16x8, H0), acc);
        acc = MFMA32(WB, __builtin_bit_cast(f16x8, H1), acc);

        // tanh(z) where acc = 2*log2(e)*z :  1 - 2/(exp2(acc)+1)
        float hv[16];
        #pragma unroll
        for (int r = 0; r < 16; ++r) {
            const float e = exp2f(acc[r]);
            hv[r] = fmaf(-2.0f, __builtin_amdgcn_rcpf(e + 1.0f), 1.0f);
        }

        // D-layout -> B-layout: 8 pk-cvt + 4 permlane32_swap, in-place so the
        // results land in B-word order {P0,P1,P2,P3} / {P4,P5,P6,P7}
        unsigned int P0 = pk_f16(hv[0],  hv[1]),  P1 = pk_f16(hv[2],  hv[3]);
        unsigned int P2 = pk_f16(hv[4],  hv[5]),  P3 = pk_f16(hv[6],  hv[7]);
        unsigned int P4 = pk_f16(hv[8],  hv[9]),  P5 = pk_f16(hv[10], hv[11]);
        unsigned int P6 = pk_f16(hv[12], hv[13]), P7 = pk_f16(hv[14], hv[15]);
        pl32swap(P0, P2);
        pl32swap(P1, P3);
        pl32swap(P4, P6);
        pl32swap(P5, P7);

        H0 = (u32x4){P0, P1, P2, P3};       // unconditional: dead columns are
        H1 = (u32x4){P4, P5, P6, P7};       // bounded garbage, already stored

        if (t == len - 1) {                 // last valid step: emit this seq
            *(u32x4*)po       = H0;
            *(u32x4*)(po + 8) = H1;
        }

        x0 = x1; x1 = x2; --off;
    }
}

// ---- MLP: weights staged in LDS; block=64 so 512 blocks cover all CUs ----
__global__ __launch_bounds__(64) void mlp_kernel(
    const _Float16* __restrict__ emb,
    const float* __restrict__ W1, const float* __restrict__ b1,
    const float* __restrict__ W2, const float* __restrict__ b2,
    const float* __restrict__ W3, const float* __restrict__ b3,
    float* __restrict__ out, int n, int featdim, int rout)
{
    extern __shared__ float smem[];
    float* sW1 = smem;                     // featdim*32
    float* sW2 = sW1 + featdim * 32;       // 1024
    float* sW3 = sW2 + 1024;               // 32*rout
    float* sB  = sW3 + 32 * rout;          // b1(32) b2(32) b3(rout)
    for (int k = threadIdx.x; k < featdim * 32; k += blockDim.x) sW1[k] = W1[k];
    for (int k = threadIdx.x; k < 1024;         k += blockDim.x) sW2[k] = W2[k];
    for (int k = threadIdx.x; k < 32 * rout;    k += blockDim.x) sW3[k] = W3[k];
    {
        int t = threadIdx.x;
        if (t < 32) {
            sB[t] = b1[t];
            if (t < rout) sB[64 + t] = b3[t];
        } else if (t < 64) {
            sB[t] = b2[t - 32];
        }
    }
    __syncthreads();

    int i = blockIdx.x * blockDim.x + threadIdx.x;
    if (i >= n) return;
    const _Float16* f = emb + (size_t)i * featdim;

    float z1[32];
    #pragma unroll
    for (int c = 0; c < 32; ++c) z1[c] = sB[c];
    for (int k = 0; k < featdim; k += 8) {
        f16x8 fv = *(const f16x8*)(f + k);          // 16B coalesced f16 load
        #pragma unroll
        for (int kk = 0; kk < 8; ++kk) {
            const float xk = (float)fv[kk];
            const float* wr = &sW1[(k + kk) * 32];
            #pragma unroll
            for (int c = 0; c < 32; c += 4) {
                float4 w = *(const float4*)(wr + c);
                z1[c]     = fmaf(xk, w.x, z1[c]);
                z1[c + 1] = fmaf(xk, w.y, z1[c + 1]);
                z1[c + 2] = fmaf(xk, w.z, z1[c + 2]);
                z1[c + 3] = fmaf(xk, w.w, z1[c + 3]);
            }
        }
    }
    #pragma unroll
    for (int c = 0; c < 32; ++c) z1[c] = fmaxf(z1[c], 0.0f);

    float z2[32];
    #pragma unroll
    for (int c = 0; c < 32; ++c) z2[c] = sB[32 + c];
    #pragma unroll
    for (int j = 0; j < 32; ++j) {
        const float zj = z1[j];
        const float* wr = &sW2[j * 32];
        #pragma unroll
        for (int c = 0; c < 32; c += 4) {
            float4 w = *(const float4*)(wr + c);
            z2[c]     = fmaf(zj, w.x, z2[c]);
            z2[c + 1] = fmaf(zj, w.y, z2[c + 1]);
            z2[c + 2] = fmaf(zj, w.z, z2[c + 2]);
            z2[c + 3] = fmaf(zj, w.w, z2[c + 3]);
        }
    }
    #pragma unroll
    for (int c = 0; c < 32; ++c) z2[c] = fmaxf(z2[c], 0.0f);

    float lo[8];
    for (int c = 0; c < rout; ++c) lo[c] = sB[64 + c];
    #pragma unroll
    for (int j = 0; j < 32; ++j) {
        const float zj = z2[j];
        for (int c = 0; c < rout; ++c)
            lo[c] = fmaf(zj, sW3[j * rout + c], lo[c]);
    }
    for (int c = 0; c < rout; ++c) out[(size_t)i * rout + c] = lo[c];
}

extern "C" void kernel_launch(void* const* d_in, const int* in_sizes, int n_in,
                              void* d_out, int out_size, void* d_ws, size_t ws_size,
                              hipStream_t stream) {
    const float* h    = (const float*)d_in[0];
    const int*   l    = (const int*)d_in[1];
    const float* W_ih = (const float*)d_in[2];
    const float* W_hh = (const float*)d_in[3];
    const float* b_ih = (const float*)d_in[4];
    const float* b_hh = (const float*)d_in[5];
    const float* W1   = (const float*)d_in[6];
    const float* b1   = (const float*)d_in[7];
    const float* W2   = (const float*)d_in[8];
    const float* b2   = (const float*)d_in[9];
    const float* W3   = (const float*)d_in[10];
    const float* b3   = (const float*)d_in[11];
    float* out = (float*)d_out;

    const int nseq = in_sizes[1];               // N*R = 131072
    const int tmax = in_sizes[0] / nseq;        // 256
    const int rout = in_sizes[10] / 32;         // R = 4
    const int n    = nseq / rout;               // 32768
    const int featdim = rout * HDIM;            // 128

    // workspace layout: emb is f16 now (8 MB)
    _Float16* emb = (_Float16*)d_ws;
    int* perm = (int*)((char*)d_ws + (size_t)nseq * HDIM * sizeof(_Float16));
    int* cnt  = perm + nseq;
    int* off  = cnt + NBINS;

    hipMemsetAsync(cnt, 0, NBINS * sizeof(int), stream);
    hist_kernel<<<64, 256, 0, stream>>>(l, cnt, nseq);
    scan_kernel<<<1, NBINS, 0, stream>>>(cnt, off);
    scatter_kernel<<<64, 256, 0, stream>>>(l, off, perm, nseq);

    // 32 seqs/wave, 1 wave/block, longest blocks dispatched first
    rnn_kernel<<<(nseq + 31) / 32, 64, 0, stream>>>(
        h, l, perm, W_ih, W_hh, b_ih, b_hh, emb, nseq, tmax);

    const int smem_bytes = (featdim * 32 + 1024 + 32 * rout + 64 + 32) * sizeof(float);
    mlp_kernel<<<(n + 63) / 64, 64, smem_bytes, stream>>>(
        emb, W1, b1, W2, b2, W3, b3, out, n, featdim, rout);
}

// Round 2
// 469.132 us; speedup vs baseline: 1.2618x; 1.1914x over previous
//
#include <hip/hip_runtime.h>

#define HDIM 32
#define NBINS 512   // lengths occupy bins 0..256; padded to pow2 for the scan

typedef _Float16 f16x8 __attribute__((ext_vector_type(8)));
typedef float f32x16 __attribute__((ext_vector_type(16)));
typedef unsigned int u32x4 __attribute__((ext_vector_type(4)));
#define MFMA32(A,B,C) __builtin_amdgcn_mfma_f32_32x32x16_f16((A),(B),(C),0,0,0)

// pack two f32 -> one u32 of 2 f16 (v_cvt_pkrtz_f16_f32, single VALU op)
__device__ __forceinline__ unsigned int pk_f16(float a, float b) {
    return __builtin_bit_cast(unsigned int, __builtin_amdgcn_cvt_pkrtz(a, b));
}
// v_permlane32_swap_b32: a_new = {a.lo, b.lo-from-partner}, b_new = {a.hi-from-partner, b.hi}
__device__ __forceinline__ void pl32swap(unsigned int& a, unsigned int& b) {
    asm("v_permlane32_swap_b32 %0, %1" : "+v"(a), "+v"(b));
}

#define PIN16(a) asm("" : "+v"(a[0]),"+v"(a[1]),"+v"(a[2]),"+v"(a[3]), \
                         "+v"(a[4]),"+v"(a[5]),"+v"(a[6]),"+v"(a[7]), \
                         "+v"(a[8]),"+v"(a[9]),"+v"(a[10]),"+v"(a[11]), \
                         "+v"(a[12]),"+v"(a[13]),"+v"(a[14]),"+v"(a[15]))
#define PIN8(a)  asm("" : "+v"(a[0]),"+v"(a[1]),"+v"(a[2]),"+v"(a[3]), \
                         "+v"(a[4]),"+v"(a[5]),"+v"(a[6]),"+v"(a[7]))

// ---- length-bucketing: counting sort into a permutation (DESCENDING) ----
__global__ __launch_bounds__(256) void hist_kernel(
    const int* __restrict__ l, int* __restrict__ cnt, int nseq)
{
    __shared__ int hc[NBINS];
    for (int k = threadIdx.x; k < NBINS; k += blockDim.x) hc[k] = 0;
    __syncthreads();
    for (int i = blockIdx.x * blockDim.x + threadIdx.x; i < nseq;
         i += gridDim.x * blockDim.x)
        atomicAdd(&hc[l[i]], 1);
    __syncthreads();
    for (int k = threadIdx.x; k < NBINS; k += blockDim.x)
        if (hc[k]) atomicAdd(&cnt[k], hc[k]);
}

// off[t] = sum_{k>t} cnt[k]  (exclusive SUFFIX sum -> longest lengths first)
__global__ __launch_bounds__(NBINS) void scan_kernel(
    const int* __restrict__ cnt, int* __restrict__ off)
{
    __shared__ int sc[NBINS];
    int t = threadIdx.x;
    int v0 = cnt[t];
    sc[t] = v0;
    __syncthreads();
    for (int d = 1; d < NBINS; d <<= 1) {
        int v = (t + d < NBINS) ? sc[t + d] : 0;
        __syncthreads();
        sc[t] += v;
        __syncthreads();
    }
    off[t] = sc[t] - v0;          // strictly-greater suffix sum
}

// Block-aggregated scatter: LDS histogram per block, ONE global atomic per
// touched bin to reserve a range, then LDS cursors for local ranks.
__global__ __launch_bounds__(256) void scatter_kernel(
    const int* __restrict__ l, int* __restrict__ off,
    int* __restrict__ perm, int nseq)
{
    __shared__ int lcur[NBINS];
    const int chunk = (nseq + gridDim.x - 1) / gridDim.x;
    const int lo = blockIdx.x * chunk;
    const int hi = min(nseq, lo + chunk);
    for (int k = threadIdx.x; k < NBINS; k += blockDim.x) lcur[k] = 0;
    __syncthreads();
    for (int i = lo + threadIdx.x; i < hi; i += blockDim.x)
        atomicAdd(&lcur[l[i]], 1);
    __syncthreads();
    for (int k = threadIdx.x; k < NBINS; k += blockDim.x) {
        int c = lcur[k];
        lcur[k] = c ? atomicAdd(&off[k], c) : 0;   // global base for this block
    }
    __syncthreads();
    for (int i = lo + threadIdx.x; i < hi; i += blockDim.x) {
        int p = atomicAdd(&lcur[l[i]], 1);         // LDS cursor = base + rank
        perm[p] = i;
    }
}

// ---- RNN: wave = 32 (length-matched) sequences, MFMA 32x32x16 f16 ----
// Lane: n = lane&31 (seq/column), half = lane>>5.
// A frag f: A[m=n][k=8*half+j] -> W_hh[n*32 + 16f + 8*half + j]   (scaled by S)
// B frag f: B[k][n=lane&31], k = 16f + 8*half + j -> h[k]
// C/D: col=lane&31, row=(r&3)+8*(r>>2)+4*half   [verified mapping]
//
// Changes this round (attacking the 4x VALU-issue inflation):
//  * x*W_ih folded into a THIRD chained MFMA on the (94% idle) matrix pipe:
//    A word0 = pk(W_ih[m]*S, 0) on half0 lanes (zero on half1), B word0 =
//    pk(x, 0) on all lanes. Dead half1 B-garbage (k=8,9) is killed by
//    A[m][8..15] == 0. Bias rides in the f32 C operand (exact path).
//    This deletes the 16 per-step FMAs AND 32 pinned VGPRs of pressure
//    (round-1 counters: VGPR=44 < pinned live set => invariants were being
//    shuttled through AGPR/scratch per step).
//  * raw v_exp_f32 via __builtin_amdgcn_exp2f (no OCML guard sequence)
//  * rest identical to the passing round-1 kernel
__global__ __launch_bounds__(64, 4) void rnn_kernel(
    const float* __restrict__ hin, const int* __restrict__ l,
    const int* __restrict__ perm,
    const float* __restrict__ W_ih, const float* __restrict__ W_hh,
    const float* __restrict__ b_ih, const float* __restrict__ b_hh,
    _Float16* __restrict__ emb, int nseq, int tmax)
{
    const int lane = threadIdx.x & 63;
    const int n    = lane & 31;
    const int half = lane >> 5;
    const int pidx = blockIdx.x * 32 + n;
    const bool live = pidx < nseq;
    const int seq  = live ? perm[pidx] : 0;
    const int len  = live ? l[seq] : 0;

    const float S = 2.8853900817779268f;   // 2*log2(e), folded into weights

    // persistent A fragments (W_hh * S in f16), pinned
    unsigned int qw[8];
    {
        f16x8 w[2];
        #pragma unroll
        for (int f = 0; f < 2; ++f)
            #pragma unroll
            for (int j = 0; j < 8; ++j)
                w[f][j] = (_Float16)(W_hh[n * 32 + 16 * f + 8 * half + j] * S);
        u32x4 qa = __builtin_bit_cast(u32x4, w[0]);
        u32x4 qb = __builtin_bit_cast(u32x4, w[1]);
        #pragma unroll
        for (int c = 0; c < 4; ++c) { qw[c] = qa[c]; qw[4 + c] = qb[c]; }
    }
    PIN8(qw);
    const f16x8 WA = __builtin_bit_cast(f16x8, (u32x4){qw[0], qw[1], qw[2], qw[3]});
    const f16x8 WB = __builtin_bit_cast(f16x8, (u32x4){qw[4], qw[5], qw[6], qw[7]});

    // input-path MFMA A-fragment: A[m][0] = W_ih[m]*S on half0, else zero
    unsigned int xaw = half ? 0u : pk_f16(W_ih[n] * S, 0.0f);
    unsigned int zz[3] = {0u, 0u, 0u};     // pinned zero words for frag quads
    asm("" : "+v"(xaw), "+v"(zz[0]), "+v"(zz[1]), "+v"(zz[2]));
    const f16x8 XA = __builtin_bit_cast(f16x8, (u32x4){xaw, zz[0], zz[1], zz[2]});

    // bias (scaled) as the f32 MFMA C operand — exact bias path, loop-invariant
    float bvS[16];
    #pragma unroll
    for (int r = 0; r < 16; ++r) {
        const int row = (r & 3) + 8 * (r >> 2) + 4 * half;
        bvS[r] = (b_ih[row] + b_hh[row]) * S;
    }
    PIN16(bvS);
    f32x16 bC;
    #pragma unroll
    for (int r = 0; r < 16; ++r) bC[r] = bvS[r];

    // trip count = max length over the wave's 32 sequences (bucketed ~equal)
    int mx = len;
    #pragma unroll
    for (int d = 1; d < 32; d <<= 1) {
        int o = __shfl_xor(mx, d);
        mx = mx > o ? mx : o;
    }
    const int maxlen = mx;

    // output pointer: emb row = 32 f16 = 16 u32; this lane owns u32s
    // [4*half .. +3] (k=8*half..+7) and [8+4*half .. +3] (k=16+8*half..+7)
    unsigned int* po = (unsigned int*)emb + (size_t)seq * 16 + 4 * half;
    if (live && len == 0) {                 // len==0 -> emb stays zero
        const u32x4 z = {0u, 0u, 0u, 0u};
        *(u32x4*)po       = z;
        *(u32x4*)(po + 8) = z;
    }

    const int base = seq * tmax;
    int off = len - 1;                      // x at step t = hin[len-1-t]
    float x0 = hin[base + (off > 0 ? off : 0)];
    float x1 = hin[base + (off - 1 > 0 ? off - 1 : 0)];

    u32x4 H0 = {0u, 0u, 0u, 0u}, H1 = {0u, 0u, 0u, 0u};   // h, f16 B-layout
    const int tstore = len - 1;

    for (int t = 0; t < maxlen; ++t) {
        const int off2 = off - 2;
        const float x2 = hin[base + (off2 > 0 ? off2 : 0)];   // depth-2 prefetch

        // input MFMA: acc = x*W_ih*S + b*S  (matrix pipe, 1 cvt + 1 mfma)
        const unsigned int xw = pk_f16(x0, 0.0f);
        const f16x8 XB = __builtin_bit_cast(f16x8, (u32x4){xw, zz[0], zz[1], zz[2]});
        f32x16 acc = MFMA32(XA, XB, bC);
        acc = MFMA32(WA, __builtin_bit_cast(f16x8, H0), acc);
        acc = MFMA32(WB, __builtin_bit_cast(f16x8, H1), acc);

        // tanh(z) where acc = 2*log2(e)*z :  1 - 2/(exp2(acc)+1)
        float hv[16];
        #pragma unroll
        for (int r = 0; r < 16; ++r) {
            const float e = __builtin_amdgcn_exp2f(acc[r]);   // bare v_exp_f32
            hv[r] = fmaf(-2.0f, __builtin_amdgcn_rcpf(e + 1.0f), 1.0f);
        }

        // D-layout -> B-layout: 8 pk-cvt + 4 permlane32_swap
        unsigned int P0 = pk_f16(hv[0],  hv[1]),  P1 = pk_f16(hv[2],  hv[3]);
        unsigned int P2 = pk_f16(hv[4],  hv[5]),  P3 = pk_f16(hv[6],  hv[7]);
        unsigned int P4 = pk_f16(hv[8],  hv[9]),  P5 = pk_f16(hv[10], hv[11]);
        unsigned int P6 = pk_f16(hv[12], hv[13]), P7 = pk_f16(hv[14], hv[15]);
        pl32swap(P0, P2);
        pl32swap(P1, P3);
        pl32swap(P4, P6);
        pl32swap(P5, P7);

        H0 = (u32x4){P0, P1, P2, P3};       // unconditional: dead columns are
        H1 = (u32x4){P4, P5, P6, P7};       // bounded garbage, already stored

        if (t == tstore) {                  // last valid step: emit this seq
            *(u32x4*)po       = H0;
            *(u32x4*)(po + 8) = H1;
        }

        x0 = x1; x1 = x2; --off;
    }
}

// ---- MLP: weights staged in LDS; block=64 so 512 blocks cover all CUs ----
__global__ __launch_bounds__(64) void mlp_kernel(
    const _Float16* __restrict__ emb,
    const float* __restrict__ W1, const float* __restrict__ b1,
    const float* __restrict__ W2, const float* __restrict__ b2,
    const float* __restrict__ W3, const float* __restrict__ b3,
    float* __restrict__ out, int n, int featdim, int rout)
{
    extern __shared__ float smem[];
    float* sW1 = smem;                     // featdim*32
    float* sW2 = sW1 + featdim * 32;       // 1024
    float* sW3 = sW2 + 1024;               // 32*rout
    float* sB  = sW3 + 32 * rout;          // b1(32) b2(32) b3(rout)
    for (int k = threadIdx.x; k < featdim * 32; k += blockDim.x) sW1[k] = W1[k];
    for (int k = threadIdx.x; k < 1024;         k += blockDim.x) sW2[k] = W2[k];
    for (int k = threadIdx.x; k < 32 * rout;    k += blockDim.x) sW3[k] = W3[k];
    {
        int t = threadIdx.x;
        if (t < 32) {
            sB[t] = b1[t];
            if (t < rout) sB[64 + t] = b3[t];
        } else if (t < 64) {
            sB[t] = b2[t - 32];
        }
    }
    __syncthreads();

    int i = blockIdx.x * blockDim.x + threadIdx.x;
    if (i >= n) return;
    const _Float16* f = emb + (size_t)i * featdim;

    float z1[32];
    #pragma unroll
    for (int c = 0; c < 32; ++c) z1[c] = sB[c];
    for (int k = 0; k < featdim; k += 8) {
        f16x8 fv = *(const f16x8*)(f + k);          // 16B coalesced f16 load
        #pragma unroll
        for (int kk = 0; kk < 8; ++kk) {
            const float xk = (float)fv[kk];
            const float* wr = &sW1[(k + kk) * 32];
            #pragma unroll
            for (int c = 0; c < 32; c += 4) {
                float4 w = *(const float4*)(wr + c);
                z1[c]     = fmaf(xk, w.x, z1[c]);
                z1[c + 1] = fmaf(xk, w.y, z1[c + 1]);
                z1[c + 2] = fmaf(xk, w.z, z1[c + 2]);
                z1[c + 3] = fmaf(xk, w.w, z1[c + 3]);
            }
        }
    }
    #pragma unroll
    for (int c = 0; c < 32; ++c) z1[c] = fmaxf(z1[c], 0.0f);

    float z2[32];
    #pragma unroll
    for (int c = 0; c < 32; ++c) z2[c] = sB[32 + c];
    #pragma unroll
    for (int j = 0; j < 32; ++j) {
        const float zj = z1[j];
        const float* wr = &sW2[j * 32];
        #pragma unroll
        for (int c = 0; c < 32; c += 4) {
            float4 w = *(const float4*)(wr + c);
            z2[c]     = fmaf(zj, w.x, z2[c]);
            z2[c + 1] = fmaf(zj, w.y, z2[c + 1]);
            z2[c + 2] = fmaf(zj, w.z, z2[c + 2]);
            z2[c + 3] = fmaf(zj, w.w, z2[c + 3]);
        }
    }
    #pragma unroll
    for (int c = 0; c < 32; ++c) z2[c] = fmaxf(z2[c], 0.0f);

    float lo[8];
    for (int c = 0; c < rout; ++c) lo[c] = sB[64 + c];
    #pragma unroll
    for (int j = 0; j < 32; ++j) {
        const float zj = z2[j];
        for (int c = 0; c < rout; ++c)
            lo[c] = fmaf(zj, sW3[j * rout + c], lo[c]);
    }
    for (int c = 0; c < rout; ++c) out[(size_t)i * rout + c] = lo[c];
}

extern "C" void kernel_launch(void* const* d_in, const int* in_sizes, int n_in,
                              void* d_out, int out_size, void* d_ws, size_t ws_size,
                              hipStream_t stream) {
    const float* h    = (const float*)d_in[0];
    const int*   l    = (const int*)d_in[1];
    const float* W_ih = (const float*)d_in[2];
    const float* W_hh = (const float*)d_in[3];
    const float* b_ih = (const float*)d_in[4];
    const float* b_hh = (const float*)d_in[5];
    const float* W1   = (const float*)d_in[6];
    const float* b1   = (const float*)d_in[7];
    const float* W2   = (const float*)d_in[8];
    const float* b2   = (const float*)d_in[9];
    const float* W3   = (const float*)d_in[10];
    const float* b3   = (const float*)d_in[11];
    float* out = (float*)d_out;

    const int nseq = in_sizes[1];               // N*R = 131072
    const int tmax = in_sizes[0] / nseq;        // 256
    const int rout = in_sizes[10] / 32;         // R = 4
    const int n    = nseq / rout;               // 32768
    const int featdim = rout * HDIM;            // 128

    // workspace layout: emb is f16 (8 MB)
    _Float16* emb = (_Float16*)d_ws;
    int* perm = (int*)((char*)d_ws + (size_t)nseq * HDIM * sizeof(_Float16));
    int* cnt  = perm + nseq;
    int* off  = cnt + NBINS;

    hipMemsetAsync(cnt, 0, NBINS * sizeof(int), stream);
    hist_kernel<<<64, 256, 0, stream>>>(l, cnt, nseq);
    scan_kernel<<<1, NBINS, 0, stream>>>(cnt, off);
    scatter_kernel<<<64, 256, 0, stream>>>(l, off, perm, nseq);

    // 32 seqs/wave, 1 wave/block, longest blocks dispatched first
    rnn_kernel<<<(nseq + 31) / 32, 64, 0, stream>>>(
        h, l, perm, W_ih, W_hh, b_ih, b_hh, emb, nseq, tmax);

    const int smem_bytes = (featdim * 32 + 1024 + 32 * rout + 64 + 32) * sizeof(float);
    mlp_kernel<<<(n + 63) / 64, 64, smem_bytes, stream>>>(
        emb, W1, b1, W2, b2, W3, b3, out, n, featdim, rout);
}

// Round 4
// 361.140 us; speedup vs baseline: 1.6391x; 1.2990x over previous
//
#include <hip/hip_runtime.h>

#define HDIM 32
#define NBINS 512   // lengths occupy bins 0..256; padded to pow2 for the scan

typedef _Float16 f16x8 __attribute__((ext_vector_type(8)));
typedef float f32x16 __attribute__((ext_vector_type(16)));
typedef unsigned int u32x4 __attribute__((ext_vector_type(4)));
#define MFMA32(A,B,C) __builtin_amdgcn_mfma_f32_32x32x16_f16((A),(B),(C),0,0,0)

// pack two f32 -> one u32 of 2 f16 (v_cvt_pkrtz_f16_f32, single VALU op)
__device__ __forceinline__ unsigned int pk_f16(float a, float b) {
    return __builtin_bit_cast(unsigned int, __builtin_amdgcn_cvt_pkrtz(a, b));
}
// v_permlane32_swap_b32 (verified semantics via the passing RNN)
__device__ __forceinline__ void pl32swap(unsigned int& a, unsigned int& b) {
    asm("v_permlane32_swap_b32 %0, %1" : "+v"(a), "+v"(b));
}

#define PIN16(a) asm("" : "+v"(a[0]),"+v"(a[1]),"+v"(a[2]),"+v"(a[3]), \
                         "+v"(a[4]),"+v"(a[5]),"+v"(a[6]),"+v"(a[7]), \
                         "+v"(a[8]),"+v"(a[9]),"+v"(a[10]),"+v"(a[11]), \
                         "+v"(a[12]),"+v"(a[13]),"+v"(a[14]),"+v"(a[15]))
#define PIN8(a)  asm("" : "+v"(a[0]),"+v"(a[1]),"+v"(a[2]),"+v"(a[3]), \
                         "+v"(a[4]),"+v"(a[5]),"+v"(a[6]),"+v"(a[7]))

// ---- length-bucketing: counting sort into a permutation (DESCENDING) ----
__global__ __launch_bounds__(256) void hist_kernel(
    const int* __restrict__ l, int* __restrict__ cnt, int nseq)
{
    __shared__ int hc[NBINS];
    for (int k = threadIdx.x; k < NBINS; k += blockDim.x) hc[k] = 0;
    __syncthreads();
    for (int i = blockIdx.x * blockDim.x + threadIdx.x; i < nseq;
         i += gridDim.x * blockDim.x)
        atomicAdd(&hc[l[i]], 1);
    __syncthreads();
    for (int k = threadIdx.x; k < NBINS; k += blockDim.x)
        if (hc[k]) atomicAdd(&cnt[k], hc[k]);
}

// off[t] = sum_{k>t} cnt[k]  (exclusive SUFFIX sum -> longest lengths first)
__global__ __launch_bounds__(NBINS) void scan_kernel(
    const int* __restrict__ cnt, int* __restrict__ off)
{
    __shared__ int sc[NBINS];
    int t = threadIdx.x;
    int v0 = cnt[t];
    sc[t] = v0;
    __syncthreads();
    for (int d = 1; d < NBINS; d <<= 1) {
        int v = (t + d < NBINS) ? sc[t + d] : 0;
        __syncthreads();
        sc[t] += v;
        __syncthreads();
    }
    off[t] = sc[t] - v0;          // strictly-greater suffix sum
}

// Block-aggregated scatter: LDS histogram per block, ONE global atomic per
// touched bin to reserve a range, then LDS cursors for local ranks.
__global__ __launch_bounds__(256) void scatter_kernel(
    const int* __restrict__ l, int* __restrict__ off,
    int* __restrict__ perm, int nseq)
{
    __shared__ int lcur[NBINS];
    const int chunk = (nseq + gridDim.x - 1) / gridDim.x;
    const int lo = blockIdx.x * chunk;
    const int hi = min(nseq, lo + chunk);
    for (int k = threadIdx.x; k < NBINS; k += blockDim.x) lcur[k] = 0;
    __syncthreads();
    for (int i = lo + threadIdx.x; i < hi; i += blockDim.x)
        atomicAdd(&lcur[l[i]], 1);
    __syncthreads();
    for (int k = threadIdx.x; k < NBINS; k += blockDim.x) {
        int c = lcur[k];
        lcur[k] = c ? atomicAdd(&off[k], c) : 0;   // global base for this block
    }
    __syncthreads();
    for (int i = lo + threadIdx.x; i < hi; i += blockDim.x) {
        int p = atomicAdd(&lcur[l[i]], 1);         // LDS cursor = base + rank
        perm[p] = i;
    }
}

// ---- RNN: wave = 32 (length-matched) sequences, MFMA 32x32x16 f16 ----
// (unchanged from round 2 — 169 us, VGPR=32, passing)
__global__ __launch_bounds__(64, 4) void rnn_kernel(
    const float* __restrict__ hin, const int* __restrict__ l,
    const int* __restrict__ perm,
    const float* __restrict__ W_ih, const float* __restrict__ W_hh,
    const float* __restrict__ b_ih, const float* __restrict__ b_hh,
    _Float16* __restrict__ emb, int nseq, int tmax)
{
    const int lane = threadIdx.x & 63;
    const int n    = lane & 31;
    const int half = lane >> 5;
    const int pidx = blockIdx.x * 32 + n;
    const bool live = pidx < nseq;
    const int seq  = live ? perm[pidx] : 0;
    const int len  = live ? l[seq] : 0;

    const float S = 2.8853900817779268f;   // 2*log2(e), folded into weights

    unsigned int qw[8];
    {
        f16x8 w[2];
        #pragma unroll
        for (int f = 0; f < 2; ++f)
            #pragma unroll
            for (int j = 0; j < 8; ++j)
                w[f][j] = (_Float16)(W_hh[n * 32 + 16 * f + 8 * half + j] * S);
        u32x4 qa = __builtin_bit_cast(u32x4, w[0]);
        u32x4 qb = __builtin_bit_cast(u32x4, w[1]);
        #pragma unroll
        for (int c = 0; c < 4; ++c) { qw[c] = qa[c]; qw[4 + c] = qb[c]; }
    }
    PIN8(qw);
    const f16x8 WA = __builtin_bit_cast(f16x8, (u32x4){qw[0], qw[1], qw[2], qw[3]});
    const f16x8 WB = __builtin_bit_cast(f16x8, (u32x4){qw[4], qw[5], qw[6], qw[7]});

    // input-path MFMA A-fragment: A[m][0] = W_ih[m]*S on half0, else zero
    unsigned int xaw = half ? 0u : pk_f16(W_ih[n] * S, 0.0f);
    unsigned int zz[3] = {0u, 0u, 0u};
    asm("" : "+v"(xaw), "+v"(zz[0]), "+v"(zz[1]), "+v"(zz[2]));
    const f16x8 XA = __builtin_bit_cast(f16x8, (u32x4){xaw, zz[0], zz[1], zz[2]});

    // bias (scaled) as the f32 MFMA C operand
    float bvS[16];
    #pragma unroll
    for (int r = 0; r < 16; ++r) {
        const int row = (r & 3) + 8 * (r >> 2) + 4 * half;
        bvS[r] = (b_ih[row] + b_hh[row]) * S;
    }
    PIN16(bvS);
    f32x16 bC;
    #pragma unroll
    for (int r = 0; r < 16; ++r) bC[r] = bvS[r];

    int mx = len;
    #pragma unroll
    for (int d = 1; d < 32; d <<= 1) {
        int o = __shfl_xor(mx, d);
        mx = mx > o ? mx : o;
    }
    const int maxlen = mx;

    unsigned int* po = (unsigned int*)emb + (size_t)seq * 16 + 4 * half;
    if (live && len == 0) {
        const u32x4 z = {0u, 0u, 0u, 0u};
        *(u32x4*)po       = z;
        *(u32x4*)(po + 8) = z;
    }

    const int base = seq * tmax;
    int off = len - 1;
    float x0 = hin[base + (off > 0 ? off : 0)];
    float x1 = hin[base + (off - 1 > 0 ? off - 1 : 0)];

    u32x4 H0 = {0u, 0u, 0u, 0u}, H1 = {0u, 0u, 0u, 0u};
    const int tstore = len - 1;

    for (int t = 0; t < maxlen; ++t) {
        const int off2 = off - 2;
        const float x2 = hin[base + (off2 > 0 ? off2 : 0)];

        const unsigned int xw = pk_f16(x0, 0.0f);
        const f16x8 XB = __builtin_bit_cast(f16x8, (u32x4){xw, zz[0], zz[1], zz[2]});
        f32x16 acc = MFMA32(XA, XB, bC);
        acc = MFMA32(WA, __builtin_bit_cast(f16x8, H0), acc);
        acc = MFMA32(WB, __builtin_bit_cast(f16x8, H1), acc);

        float hv[16];
        #pragma unroll
        for (int r = 0; r < 16; ++r) {
            const float e = __builtin_amdgcn_exp2f(acc[r]);
            hv[r] = fmaf(-2.0f, __builtin_amdgcn_rcpf(e + 1.0f), 1.0f);
        }

        unsigned int P0 = pk_f16(hv[0],  hv[1]),  P1 = pk_f16(hv[2],  hv[3]);
        unsigned int P2 = pk_f16(hv[4],  hv[5]),  P3 = pk_f16(hv[6],  hv[7]);
        unsigned int P4 = pk_f16(hv[8],  hv[9]),  P5 = pk_f16(hv[10], hv[11]);
        unsigned int P6 = pk_f16(hv[12], hv[13]), P7 = pk_f16(hv[14], hv[15]);
        pl32swap(P0, P2);
        pl32swap(P1, P3);
        pl32swap(P4, P6);
        pl32swap(P5, P7);

        H0 = (u32x4){P0, P1, P2, P3};
        H1 = (u32x4){P4, P5, P6, P7};

        if (t == tstore) {
            *(u32x4*)po       = H0;
            *(u32x4*)(po + 8) = H1;
        }

        x0 = x1; x1 = x2; --off;
    }
}

// ---- MLP, compile-time-specialized scalar version ----
// Round-2's scalar MLP was CORRECT but catastrophically slow (199us):
// VGPR=256, WRITE_SIZE=76MB (scratch spills), VALUBusy=0.02% — the
// runtime featdim/rout loop bounds defeated the register allocator.
// This version: all dims compile-time, all loops statically bounded,
// float4 LDS broadcast reads, scalar accumulators. Roofline ~5us
// (8MB emb read + 512KB write + 345 MFLOP fp32). fp32-exact math.
// (An MFMA-based MLP was tried in round 3 and produced NaN for reasons
// not identifiable statically; since the op is memory/launch-bound, the
// matrix pipe offers no headroom here anyway — scalar is the right tool.)
template<int FEATDIM, int ROUT>
__global__ __launch_bounds__(256) void mlp_spec_kernel(
    const _Float16* __restrict__ emb,
    const float* __restrict__ W1, const float* __restrict__ b1,
    const float* __restrict__ W2, const float* __restrict__ b2,
    const float* __restrict__ W3, const float* __restrict__ b3,
    float* __restrict__ out, int n)
{
    __shared__ float sW1[FEATDIM * 32];
    __shared__ float sW2[32 * 32];
    __shared__ float sW3[32 * ROUT];
    __shared__ float sB[64 + ROUT];
    for (int k = threadIdx.x; k < FEATDIM * 32; k += 256) sW1[k] = W1[k];
    for (int k = threadIdx.x; k < 32 * 32;      k += 256) sW2[k] = W2[k];
    if (threadIdx.x < 32 * ROUT) sW3[threadIdx.x] = W3[threadIdx.x];
    if (threadIdx.x < 32)                 sB[threadIdx.x] = b1[threadIdx.x];
    else if (threadIdx.x < 64)            sB[threadIdx.x] = b2[threadIdx.x - 32];
    else if (threadIdx.x < 64 + ROUT)     sB[threadIdx.x] = b3[threadIdx.x - 64];
    __syncthreads();

    const int i = blockIdx.x * 256 + threadIdx.x;
    if (i >= n) return;
    const _Float16* f = emb + (size_t)i * FEATDIM;

    float z1[32];
    #pragma unroll
    for (int c = 0; c < 32; ++c) z1[c] = sB[c];
    #pragma unroll 2
    for (int k = 0; k < FEATDIM; k += 8) {
        const f16x8 fv = *(const f16x8*)(f + k);      // 16B coalesced load
        #pragma unroll
        for (int kk = 0; kk < 8; ++kk) {
            const float xk = (float)fv[kk];
            const float* wr = &sW1[(k + kk) * 32];    // uniform addr: broadcast
            #pragma unroll
            for (int c = 0; c < 32; c += 4) {
                const float4 w = *(const float4*)(wr + c);
                z1[c]     = fmaf(xk, w.x, z1[c]);
                z1[c + 1] = fmaf(xk, w.y, z1[c + 1]);
                z1[c + 2] = fmaf(xk, w.z, z1[c + 2]);
                z1[c + 3] = fmaf(xk, w.w, z1[c + 3]);
            }
        }
    }
    #pragma unroll
    for (int c = 0; c < 32; ++c) z1[c] = fmaxf(z1[c], 0.0f);

    float z2[32];
    #pragma unroll
    for (int c = 0; c < 32; ++c) z2[c] = sB[32 + c];
    #pragma unroll 4
    for (int j = 0; j < 32; ++j) {
        const float zj = z1[j];
        const float* wr = &sW2[j * 32];
        #pragma unroll
        for (int c = 0; c < 32; c += 4) {
            const float4 w = *(const float4*)(wr + c);
            z2[c]     = fmaf(zj, w.x, z2[c]);
            z2[c + 1] = fmaf(zj, w.y, z2[c + 1]);
            z2[c + 2] = fmaf(zj, w.z, z2[c + 2]);
            z2[c + 3] = fmaf(zj, w.w, z2[c + 3]);
        }
    }
    #pragma unroll
    for (int c = 0; c < 32; ++c) z2[c] = fmaxf(z2[c], 0.0f);

    float lo[ROUT];
    #pragma unroll
    for (int c = 0; c < ROUT; ++c) lo[c] = sB[64 + c];
    #pragma unroll
    for (int j = 0; j < 32; ++j) {
        const float zj = z2[j];
        #pragma unroll
        for (int c = 0; c < ROUT; ++c)
            lo[c] = fmaf(zj, sW3[j * ROUT + c], lo[c]);
    }
    if (ROUT == 4) {
        *(float4*)(out + (size_t)i * 4) = make_float4(lo[0], lo[1], lo[2], lo[3]);
    } else {
        #pragma unroll
        for (int c = 0; c < ROUT; ++c) out[(size_t)i * ROUT + c] = lo[c];
    }
}

// ---- generic fallback MLP (off-path for this problem; passed rounds 0-2) ----
__global__ __launch_bounds__(64) void mlp_kernel(
    const _Float16* __restrict__ emb,
    const float* __restrict__ W1, const float* __restrict__ b1,
    const float* __restrict__ W2, const float* __restrict__ b2,
    const float* __restrict__ W3, const float* __restrict__ b3,
    float* __restrict__ out, int n, int featdim, int rout)
{
    extern __shared__ float smem[];
    float* sW1 = smem;
    float* sW2 = sW1 + featdim * 32;
    float* sW3 = sW2 + 1024;
    float* sB  = sW3 + 32 * rout;
    for (int k = threadIdx.x; k < featdim * 32; k += blockDim.x) sW1[k] = W1[k];
    for (int k = threadIdx.x; k < 1024;         k += blockDim.x) sW2[k] = W2[k];
    for (int k = threadIdx.x; k < 32 * rout;    k += blockDim.x) sW3[k] = W3[k];
    {
        int t = threadIdx.x;
        if (t < 32) {
            sB[t] = b1[t];
            if (t < rout) sB[64 + t] = b3[t];
        } else if (t < 64) {
            sB[t] = b2[t - 32];
        }
    }
    __syncthreads();

    int i = blockIdx.x * blockDim.x + threadIdx.x;
    if (i >= n) return;
    const _Float16* f = emb + (size_t)i * featdim;

    float z1[32];
    #pragma unroll
    for (int c = 0; c < 32; ++c) z1[c] = sB[c];
    for (int k = 0; k < featdim; k += 8) {
        f16x8 fv = *(const f16x8*)(f + k);
        #pragma unroll
        for (int kk = 0; kk < 8; ++kk) {
            const float xk = (float)fv[kk];
            const float* wr = &sW1[(k + kk) * 32];
            #pragma unroll
            for (int c = 0; c < 32; ++c) z1[c] = fmaf(xk, wr[c], z1[c]);
        }
    }
    #pragma unroll
    for (int c = 0; c < 32; ++c) z1[c] = fmaxf(z1[c], 0.0f);

    float z2[32];
    #pragma unroll
    for (int c = 0; c < 32; ++c) z2[c] = sB[32 + c];
    #pragma unroll
    for (int j = 0; j < 32; ++j) {
        const float zj = z1[j];
        const float* wr = &sW2[j * 32];
        #pragma unroll
        for (int c = 0; c < 32; ++c) z2[c] = fmaf(zj, wr[c], z2[c]);
    }
    #pragma unroll
    for (int c = 0; c < 32; ++c) z2[c] = fmaxf(z2[c], 0.0f);

    for (int c = 0; c < rout; ++c) {
        float lo = sB[64 + c];
        #pragma unroll
        for (int j = 0; j < 32; ++j) lo = fmaf(z2[j], sW3[j * rout + c], lo);
        out[(size_t)i * rout + c] = lo;
    }
}

extern "C" void kernel_launch(void* const* d_in, const int* in_sizes, int n_in,
                              void* d_out, int out_size, void* d_ws, size_t ws_size,
                              hipStream_t stream) {
    const float* h    = (const float*)d_in[0];
    const int*   l    = (const int*)d_in[1];
    const float* W_ih = (const float*)d_in[2];
    const float* W_hh = (const float*)d_in[3];
    const float* b_ih = (const float*)d_in[4];
    const float* b_hh = (const float*)d_in[5];
    const float* W1   = (const float*)d_in[6];
    const float* b1   = (const float*)d_in[7];
    const float* W2   = (const float*)d_in[8];
    const float* b2   = (const float*)d_in[9];
    const float* W3   = (const float*)d_in[10];
    const float* b3   = (const float*)d_in[11];
    float* out = (float*)d_out;

    const int nseq = in_sizes[1];               // N*R = 131072
    const int tmax = in_sizes[0] / nseq;        // 256
    const int rout = in_sizes[10] / 32;         // R = 4
    const int n    = nseq / rout;               // 32768
    const int featdim = rout * HDIM;            // 128

    // workspace layout: emb is f16 (8 MB)
    _Float16* emb = (_Float16*)d_ws;
    int* perm = (int*)((char*)d_ws + (size_t)nseq * HDIM * sizeof(_Float16));
    int* cnt  = perm + nseq;
    int* off  = cnt + NBINS;

    hipMemsetAsync(cnt, 0, NBINS * sizeof(int), stream);
    hist_kernel<<<64, 256, 0, stream>>>(l, cnt, nseq);
    scan_kernel<<<1, NBINS, 0, stream>>>(cnt, off);
    scatter_kernel<<<64, 256, 0, stream>>>(l, off, perm, nseq);

    // 32 seqs/wave, 1 wave/block, longest blocks dispatched first
    rnn_kernel<<<(nseq + 31) / 32, 64, 0, stream>>>(
        h, l, perm, W_ih, W_hh, b_ih, b_hh, emb, nseq, tmax);

    if (featdim == 128 && rout == 4) {
        mlp_spec_kernel<128, 4><<<(n + 255) / 256, 256, 0, stream>>>(
            emb, W1, b1, W2, b2, W3, b3, out, n);
    } else {
        const int smem_bytes =
            (featdim * 32 + 1024 + 32 * rout + 64 + 32) * sizeof(float);
        mlp_kernel<<<(n + 63) / 64, 64, smem_bytes, stream>>>(
            emb, W1, b1, W2, b2, W3, b3, out, n, featdim, rout);
    }
}